// Round 2
// baseline (1429.287 us; speedup 1.0000x reference)
//
#include <hip/hip_runtime.h>
#include <hip/hip_bf16.h>

// APPNP: h = MLP(x); h_{t+1} = 0.9 * (D^-1/2 (A+I) D^-1/2) h_t + 0.1 * h0, K=10
// Self-adapting to harness storage: probes (a) float tensors bf16 vs fp32,
// (b) edge_index int32 vs int64. All gather/scatter indices clamped to [0,N)
// so no input interpretation can produce NaN/OOB.

typedef __attribute__((ext_vector_type(8))) short short8;   // 8 bf16 = 4 VGPRs
typedef __attribute__((ext_vector_type(4))) float floatx4;

#define IN_CH 512
#define HID_CH 256
#define OUT_CH 64

static __device__ inline unsigned short bf16_bits(float f) {
    __hip_bfloat16 b = __float2bfloat16(f);
    union { __hip_bfloat16 b; unsigned short u; } u2; u2.b = b; return u2.u;
}

// meta[0] = 1 iff edges stored as int32 words; meta[1] = 1 iff float tensors are fp32
__global__ void k_probe(const int* __restrict__ e, long long ewords,
                        const unsigned short* __restrict__ xw,
                        int* __restrict__ meta) {
    // (a) edges: sample odd 32-bit words across the first `ewords` words
    //     (safe under both interpretations). int64 little-endian node ids
    //     (< 2^31) have all-zero odd words; int32 ids are ~never all zero.
    int any = 0;
    long long half = ewords >> 1;
    long long step = half / 4096; if (step < 1) step = 1;
    for (long long i = threadIdx.x; i < 4096; i += blockDim.x) {
        long long idx = 2 * (i * step) + 1;
        if (idx < ewords) any |= e[idx];
    }
    if (any) atomicOr(&meta[0], 1);
    // (b) floats: genuine bf16 N(0,1) data never has exponent 0xFF; fp32 data
    //     read as bf16 half-words hits exp==0xFF with p~2^-9 per word.
    int bad = 0;
    for (int i = threadIdx.x; i < 65536; i += blockDim.x) {
        unsigned short w = xw[i];
        if ((w & 0x7F80) == 0x7F80) bad = 1;
    }
    if (bad) atomicOr(&meta[1], 1);
}

__global__ void k_transpose(const void* __restrict__ w,
                            __hip_bfloat16* __restrict__ wt, int K, int N,
                            const int* __restrict__ meta) {
    int f32 = meta[1];
    int i = blockIdx.x * blockDim.x + threadIdx.x;
    if (i < K * N) {
        int k = i / N, n = i - k * N;
        __hip_bfloat16 v = f32 ? __float2bfloat16(((const float*)w)[i])
                               : ((const __hip_bfloat16*)w)[i];
        wt[n * K + k] = v;
    }
}

__global__ void k_count(const int* __restrict__ e, const int* __restrict__ meta,
                        int E, int* __restrict__ cnt, int n) {
    int is32 = meta[0];
    int j = blockIdx.x * 256 + threadIdx.x;
    if (j < E) {
        long long idx = (long long)E + j;
        int d = is32 ? e[idx] : (int)((const long long*)e)[idx];
        if ((unsigned)d >= (unsigned)n) d = 0;   // clamp: no-op if input sane
        atomicAdd(&cnt[d], 1);
    }
}

// Hillis-Steele inclusive scan, 1024/block
__global__ __launch_bounds__(1024) void k_scan1(const int* __restrict__ cnt,
                                                int* __restrict__ incl,
                                                int* __restrict__ bsum, int n) {
    __shared__ int s[1024];
    int i = blockIdx.x * 1024 + threadIdx.x;
    int v = (i < n) ? cnt[i] : 0;
    s[threadIdx.x] = v;
    __syncthreads();
    for (int off = 1; off < 1024; off <<= 1) {
        int t = (threadIdx.x >= off) ? s[threadIdx.x - off] : 0;
        __syncthreads();
        s[threadIdx.x] += t;
        __syncthreads();
    }
    incl[blockIdx.x * 1024 + threadIdx.x] = s[threadIdx.x];
    if (threadIdx.x == 1023) bsum[blockIdx.x] = s[1023];
}

__global__ void k_scan2(const int* __restrict__ bsum, int* __restrict__ boff, int nb) {
    if (blockIdx.x == 0 && threadIdx.x == 0) {
        int a = 0;
        for (int i = 0; i < nb; ++i) { boff[i] = a; a += bsum[i]; }
    }
}

__global__ void k_scan3(const int* __restrict__ incl, const int* __restrict__ cnt,
                        const int* __restrict__ boff, int* __restrict__ rowptr,
                        int* __restrict__ cursor, int n, int E) {
    int i = blockIdx.x * 256 + threadIdx.x;
    if (i < n) {
        int r = incl[i] - cnt[i] + boff[i >> 10];  // exclusive
        rowptr[i] = r;
        cursor[i] = r;
    }
    if (i == 0) rowptr[n] = E;
}

__global__ void k_dinv(const int* __restrict__ cnt, float* __restrict__ dinv, int n) {
    int i = blockIdx.x * 256 + threadIdx.x;
    if (i < n) dinv[i] = rsqrtf((float)cnt[i] + 1.0f);  // +1 for self-loop
}

__global__ void k_fill(const int* __restrict__ e, const int* __restrict__ meta, int E,
                       int* __restrict__ cursor, int* __restrict__ col,
                       float* __restrict__ val, const float* __restrict__ dinv, int n) {
    int is32 = meta[0];
    int j = blockIdx.x * 256 + threadIdx.x;
    if (j < E) {
        int s, d;
        if (is32) { s = e[j]; d = e[(long long)E + j]; }
        else {
            const long long* e64 = (const long long*)e;
            s = (int)e64[j]; d = (int)e64[(long long)E + j];
        }
        if ((unsigned)s >= (unsigned)n) s = 0;   // clamp (same as k_count)
        if ((unsigned)d >= (unsigned)n) d = 0;
        int pos = atomicAdd(&cursor[d], 1);
        col[pos] = s;
        val[pos] = dinv[s] * dinv[d];
    }
}

// ---------- MFMA GEMM: C[M,N] = A[M,K] @ Bt[N,K]^T + bias ----------
// 64x64 tile, 4 waves (2x2 of 32x32 built from 16x16x32 MFMAs), BK=64.
// LDS row stride 72 shorts (pad 8) -> only 2-way bank aliasing (free).
// AMETA: A/bias dtype follows meta[1] (fp32 vs bf16); else A is bf16.
template<int RELU, int OUT_F32, int AMETA>
__global__ __launch_bounds__(256) void k_gemm(
    const void* __restrict__ A,
    const __hip_bfloat16* __restrict__ Bt,
    const void* __restrict__ bias,
    __hip_bfloat16* __restrict__ Cb,
    float* __restrict__ Cf,
    int M, int N, int K, const int* __restrict__ meta)
{
    __shared__ __attribute__((aligned(16))) short As[64 * 72];
    __shared__ __attribute__((aligned(16))) short Bs[64 * 72];
    const int f32 = AMETA ? meta[1] : 0;      // wave-uniform
    const int t = threadIdx.x;
    const int bm = blockIdx.x * 64;
    const int bn = blockIdx.y * 64;
    const int wave = t >> 6, lane = t & 63;
    const int wm = (wave >> 1) * 32, wn = (wave & 1) * 32;
    const int quad = lane >> 4, l16 = lane & 15;

    floatx4 zero4 = {0.0f, 0.0f, 0.0f, 0.0f};
    floatx4 acc[2][2];
    for (int i = 0; i < 2; ++i)
        for (int j = 0; j < 2; ++j) acc[i][j] = zero4;

    const __hip_bfloat16* Ab = (const __hip_bfloat16*)A;
    const float* Af = (const float*)A;

    for (int k0 = 0; k0 < K; k0 += 64) {
        __syncthreads();
        // stage 64x64 bf16 tiles; 512 chunks of 8 elements, 2 per thread
        for (int ch = t; ch < 512; ch += 256) {
            int row = ch >> 3;
            int off = (ch & 7) * 8;  // element offset within row slice
            uint4 av = {0u, 0u, 0u, 0u};
            int gr = bm + row;
            if (gr < M) {
                if (AMETA && f32) {
                    const float* p = Af + (size_t)gr * K + k0 + off;
                    union { uint4 q; unsigned short us[8]; } u;
#pragma unroll
                    for (int i = 0; i < 8; ++i) u.us[i] = bf16_bits(p[i]);
                    av = u.q;
                } else {
                    av = *(const uint4*)((const char*)Ab + ((size_t)gr * K + k0 + off) * 2);
                }
            }
            *(uint4*)((char*)As + row * 144 + off * 2) = av;
            uint4 bv = *(const uint4*)((const char*)Bt + ((size_t)(bn + row) * K + k0 + off) * 2);
            *(uint4*)((char*)Bs + row * 144 + off * 2) = bv;
        }
        __syncthreads();
#pragma unroll
        for (int kk = 0; kk < 64; kk += 32) {
            short8 af[2], bf[2];
#pragma unroll
            for (int i = 0; i < 2; ++i)
                af[i] = *(const short8*)((const char*)As + (wm + i * 16 + l16) * 144 + (kk + quad * 8) * 2);
#pragma unroll
            for (int j = 0; j < 2; ++j)
                bf[j] = *(const short8*)((const char*)Bs + (wn + j * 16 + l16) * 144 + (kk + quad * 8) * 2);
#pragma unroll
            for (int i = 0; i < 2; ++i)
#pragma unroll
                for (int j = 0; j < 2; ++j)
                    acc[i][j] = __builtin_amdgcn_mfma_f32_16x16x32_bf16(af[i], bf[j], acc[i][j], 0, 0, 0);
        }
    }

    // epilogue: C/D layout col=lane&15, row=quad*4+reg (HW-verified mapping)
#pragma unroll
    for (int i = 0; i < 2; ++i) {
#pragma unroll
        for (int j = 0; j < 2; ++j) {
            int nn = bn + wn + j * 16 + l16;
            float bv = f32 ? ((const float*)bias)[nn]
                           : __bfloat162float(((const __hip_bfloat16*)bias)[nn]);
#pragma unroll
            for (int r = 0; r < 4; ++r) {
                int m = bm + wm + i * 16 + quad * 4 + r;
                if (m < M) {
                    float v = acc[i][j][r] + bv;
                    if (RELU) v = fmaxf(v, 0.0f);
                    if (OUT_F32) Cf[(size_t)m * N + nn] = v;
                    else Cb[(size_t)m * N + nn] = __float2bfloat16(v);
                }
            }
        }
    }
}

// ---------- pull-style propagation: 16 lanes per node, float4 per lane ----------
template<int FINAL>
__global__ __launch_bounds__(256) void k_prop(
    const float* __restrict__ hc, const float* __restrict__ h0,
    const int* __restrict__ rowptr, const int* __restrict__ col,
    const float* __restrict__ val, const float* __restrict__ dinv,
    float* __restrict__ outf, void* __restrict__ outfinal, int n,
    const int* __restrict__ meta)
{
    int gid = blockIdx.x * 16 + (threadIdx.x >> 4);
    if (gid >= n) return;
    int lane = threadIdx.x & 15;
    const float4* hc4 = (const float4*)hc;

    float4 sv = hc4[(size_t)gid * 16 + lane];  // self row
    float dv = dinv[gid];
    float w = dv * dv;                          // self-loop norm
    float ax = w * sv.x, ay = w * sv.y, az = w * sv.z, aw = w * sv.w;

    int e0 = rowptr[gid], e1 = rowptr[gid + 1];
    for (int e = e0; e < e1; ++e) {
        int c = col[e];
        if ((unsigned)c >= (unsigned)n) c = 0;  // clamp: no-op if CSR sane
        float v = val[e];
        float4 hv = hc4[(size_t)c * 16 + lane];
        ax = fmaf(v, hv.x, ax);
        ay = fmaf(v, hv.y, ay);
        az = fmaf(v, hv.z, az);
        aw = fmaf(v, hv.w, aw);
    }
    float4 zv = ((const float4*)h0)[(size_t)gid * 16 + lane];
    float ox = 0.9f * ax + 0.1f * zv.x;
    float oy = 0.9f * ay + 0.1f * zv.y;
    float oz = 0.9f * az + 0.1f * zv.z;
    float ow = 0.9f * aw + 0.1f * zv.w;

    if (FINAL) {
        if (meta[1]) {  // fp32 output storage
            float4 o; o.x = ox; o.y = oy; o.z = oz; o.w = ow;
            ((float4*)outfinal)[(size_t)gid * 16 + lane] = o;
        } else {
            struct alignas(8) BF4 { unsigned short v[4]; } o;
            o.v[0] = bf16_bits(ox);
            o.v[1] = bf16_bits(oy);
            o.v[2] = bf16_bits(oz);
            o.v[3] = bf16_bits(ow);
            *(BF4*)((unsigned short*)outfinal + (size_t)gid * 64 + lane * 4) = o;
        }
    } else {
        float4 o; o.x = ox; o.y = oy; o.z = oz; o.w = ow;
        ((float4*)outf)[(size_t)gid * 16 + lane] = o;
    }
}

extern "C" void kernel_launch(void* const* d_in, const int* in_sizes, int n_in,
                              void* d_out, int out_size, void* d_ws, size_t ws_size,
                              hipStream_t stream) {
    const void* x   = d_in[0];
    const int* edges = (const int*)d_in[1];
    const void* w1  = d_in[2];
    const void* b1  = d_in[3];
    const void* w2  = d_in[4];
    const void* b2  = d_in[5];

    const int N = in_sizes[0] / IN_CH;   // 100000
    const int E = in_sizes[1] / 2;       // 1600000
    const int NB = (N + 1023) / 1024;

    size_t off = 0;
    auto carve = [&](size_t bytes) -> void* {
        void* r = (char*)d_ws + off;
        off += (bytes + 255) & ~(size_t)255;
        return r;
    };
    __hip_bfloat16* h1  = (__hip_bfloat16*)carve((size_t)N * HID_CH * 2);
    float* h0           = (float*)carve((size_t)N * OUT_CH * 4);
    float* hA           = (float*)carve((size_t)N * OUT_CH * 4);
    float* hB           = (float*)carve((size_t)N * OUT_CH * 4);
    __hip_bfloat16* w1t = (__hip_bfloat16*)carve((size_t)IN_CH * HID_CH * 2);
    __hip_bfloat16* w2t = (__hip_bfloat16*)carve((size_t)HID_CH * OUT_CH * 2);
    int* cnt            = (int*)carve((size_t)N * 4);
    int* incl           = (int*)carve((size_t)NB * 1024 * 4);
    int* bsum           = (int*)carve(1024 * 4);
    int* boff           = (int*)carve(1024 * 4);
    int* rowptr         = (int*)carve((size_t)(N + 1) * 4);
    int* cursor         = (int*)carve((size_t)N * 4);
    float* dinv         = (float*)carve((size_t)N * 4);
    int* col            = (int*)carve((size_t)E * 4);
    float* val          = (float*)carve((size_t)E * 4);
    int* meta           = (int*)carve(256);
    if (off > ws_size) return;

    hipMemsetAsync(cnt, 0, (size_t)N * 4, stream);
    hipMemsetAsync(meta, 0, 8, stream);

    k_probe<<<1, 256, 0, stream>>>(edges, (long long)2 * E,
                                   (const unsigned short*)x, meta);

    k_transpose<<<(IN_CH * HID_CH + 255) / 256, 256, 0, stream>>>(w1, w1t, IN_CH, HID_CH, meta);
    k_transpose<<<(HID_CH * OUT_CH + 255) / 256, 256, 0, stream>>>(w2, w2t, HID_CH, OUT_CH, meta);

    const int MB = (N + 63) / 64;
    k_gemm<1, 0, 1><<<dim3(MB, HID_CH / 64), 256, 0, stream>>>(
        x, w1t, b1, h1, nullptr, N, HID_CH, IN_CH, meta);
    k_gemm<0, 1, 0><<<dim3(MB, OUT_CH / 64), 256, 0, stream>>>(
        h1, w2t, b2, nullptr, h0, N, OUT_CH, HID_CH, meta);

    const int EB = (E + 255) / 256;
    k_count<<<EB, 256, 0, stream>>>(edges, meta, E, cnt, N);
    k_scan1<<<NB, 1024, 0, stream>>>(cnt, incl, bsum, N);
    k_scan2<<<1, 64, 0, stream>>>(bsum, boff, NB);
    k_scan3<<<(N + 255) / 256, 256, 0, stream>>>(incl, cnt, boff, rowptr, cursor, N, E);
    k_dinv<<<(N + 255) / 256, 256, 0, stream>>>(cnt, dinv, N);
    k_fill<<<EB, 256, 0, stream>>>(edges, meta, E, cursor, col, val, dinv, N);

    const int PB = (N + 15) / 16;
    const float* cur = h0;
    float* bufs[2] = {hA, hB};
    for (int it = 0; it < 10; ++it) {
        if (it < 9) {
            float* o = bufs[it & 1];
            k_prop<0><<<PB, 256, 0, stream>>>(cur, h0, rowptr, col, val, dinv, o, nullptr, N, meta);
            cur = o;
        } else {
            k_prop<1><<<PB, 256, 0, stream>>>(cur, h0, rowptr, col, val, dinv, nullptr, d_out, N, meta);
        }
    }
}

// Round 3
// 1036.818 us; speedup vs baseline: 1.3785x; 1.3785x over previous
//
#include <hip/hip_runtime.h>
#include <hip/hip_bf16.h>

// APPNP: h = MLP(x); h_{t+1} = 0.9 * (D^-1/2 (A+I) D^-1/2) h_t + 0.1 * h0, K=10
// Round 3:
//  - Propagation in g-space (g = dinv*h, fp16): per-edge val multiply and the
//    val[] array are gone; inner loop = pure gather-sum of fp16 rows,
//    8 lanes/node x 16B, edge loop unrolled x4. fp32 accumulation.
//  - GEMM1: 64x256 block tile (full N in one block) -> A read once from HBM.
//  - GEMM2: epilogue writes h0 (fp16) and g0 = dinv*h0 (fp16) directly.

typedef __attribute__((ext_vector_type(8))) short short8;     // 8 bf16
typedef __attribute__((ext_vector_type(4))) float floatx4;
typedef __attribute__((ext_vector_type(8))) _Float16 half8;   // 8 fp16 = 16B

#define IN_CH 512
#define HID_CH 256
#define OUT_CH 64

static __device__ inline unsigned short bf16_bits(float f) {
    __hip_bfloat16 b = __float2bfloat16(f);
    union { __hip_bfloat16 b; unsigned short u; } u2; u2.b = b; return u2.u;
}

// meta[0]=1 iff edges are int32 words; meta[1]=1 iff float tensors are fp32
__global__ void k_probe(const int* __restrict__ e, long long ewords,
                        const unsigned short* __restrict__ xw,
                        int* __restrict__ meta) {
    int any = 0;
    long long half = ewords >> 1;
    long long step = half / 4096; if (step < 1) step = 1;
    for (long long i = threadIdx.x; i < 4096; i += blockDim.x) {
        long long idx = 2 * (i * step) + 1;
        if (idx < ewords) any |= e[idx];
    }
    if (any) atomicOr(&meta[0], 1);
    int bad = 0;
    for (int i = threadIdx.x; i < 65536; i += blockDim.x) {
        unsigned short w = xw[i];
        if ((w & 0x7F80) == 0x7F80) bad = 1;   // bf16 inf/nan impossible in N(0,1) data
    }
    if (bad) atomicOr(&meta[1], 1);
}

__global__ void k_transpose(const void* __restrict__ w,
                            __hip_bfloat16* __restrict__ wt, int K, int N,
                            const int* __restrict__ meta) {
    int f32 = meta[1];
    int i = blockIdx.x * blockDim.x + threadIdx.x;
    if (i < K * N) {
        int k = i / N, n = i - k * N;
        __hip_bfloat16 v = f32 ? __float2bfloat16(((const float*)w)[i])
                               : ((const __hip_bfloat16*)w)[i];
        wt[n * K + k] = v;
    }
}

__global__ void k_count(const int* __restrict__ e, const int* __restrict__ meta,
                        int E, int* __restrict__ cnt, int n) {
    int is32 = meta[0];
    int j = blockIdx.x * 256 + threadIdx.x;
    if (j < E) {
        long long idx = (long long)E + j;
        int d = is32 ? e[idx] : (int)((const long long*)e)[idx];
        if ((unsigned)d >= (unsigned)n) d = 0;
        atomicAdd(&cnt[d], 1);
    }
}

__global__ __launch_bounds__(1024) void k_scan1(const int* __restrict__ cnt,
                                                int* __restrict__ incl,
                                                int* __restrict__ bsum, int n) {
    __shared__ int s[1024];
    int i = blockIdx.x * 1024 + threadIdx.x;
    int v = (i < n) ? cnt[i] : 0;
    s[threadIdx.x] = v;
    __syncthreads();
    for (int off = 1; off < 1024; off <<= 1) {
        int t = (threadIdx.x >= off) ? s[threadIdx.x - off] : 0;
        __syncthreads();
        s[threadIdx.x] += t;
        __syncthreads();
    }
    incl[blockIdx.x * 1024 + threadIdx.x] = s[threadIdx.x];
    if (threadIdx.x == 1023) bsum[blockIdx.x] = s[1023];
}

__global__ void k_scan2(const int* __restrict__ bsum, int* __restrict__ boff, int nb) {
    if (blockIdx.x == 0 && threadIdx.x == 0) {
        int a = 0;
        for (int i = 0; i < nb; ++i) { boff[i] = a; a += bsum[i]; }
    }
}

__global__ void k_scan3(const int* __restrict__ incl, const int* __restrict__ cnt,
                        const int* __restrict__ boff, int* __restrict__ rowptr,
                        int* __restrict__ cursor, int n, int E) {
    int i = blockIdx.x * 256 + threadIdx.x;
    if (i < n) {
        int r = incl[i] - cnt[i] + boff[i >> 10];
        rowptr[i] = r;
        cursor[i] = r;
    }
    if (i == 0) rowptr[n] = E;
}

__global__ void k_dinv(const int* __restrict__ cnt, float* __restrict__ dinv, int n) {
    int i = blockIdx.x * 256 + threadIdx.x;
    if (i < n) dinv[i] = rsqrtf((float)cnt[i] + 1.0f);  // +1 self-loop
}

__global__ void k_fill(const int* __restrict__ e, const int* __restrict__ meta, int E,
                       int* __restrict__ cursor, int* __restrict__ col, int n) {
    int is32 = meta[0];
    int j = blockIdx.x * 256 + threadIdx.x;
    if (j < E) {
        int s, d;
        if (is32) { s = e[j]; d = e[(long long)E + j]; }
        else {
            const long long* e64 = (const long long*)e;
            s = (int)e64[j]; d = (int)e64[(long long)E + j];
        }
        if ((unsigned)s >= (unsigned)n) s = 0;
        if ((unsigned)d >= (unsigned)n) d = 0;
        int pos = atomicAdd(&cursor[d], 1);
        col[pos] = s;
    }
}

// ---------- GEMM1: h1[M,256] = relu(x[M,512] @ w1 + b1), bf16 out ----------
// Block tile 64(M) x 256(N) -> A read ONCE from HBM. BK=64.
// 4 waves: wm=(w&1)*32, wn=(w>>1)*128; wave tile 32x128 = 2x8 mfma 16x16x32.
__global__ __launch_bounds__(256) void k_gemm1(
    const void* __restrict__ A, const __hip_bfloat16* __restrict__ Bt,
    const void* __restrict__ bias, __hip_bfloat16* __restrict__ C,
    int M, const int* __restrict__ meta)
{
    __shared__ __attribute__((aligned(16))) short As[64 * 72];
    __shared__ __attribute__((aligned(16))) short Bs[256 * 72];
    const int f32 = meta[1];
    const int t = threadIdx.x;
    const int bm = blockIdx.x * 64;
    const int wave = t >> 6, lane = t & 63;
    const int wm = (wave & 1) * 32, wn = (wave >> 1) * 128;
    const int quad = lane >> 4, l16 = lane & 15;

    floatx4 acc[2][8];
#pragma unroll
    for (int i = 0; i < 2; ++i)
#pragma unroll
        for (int j = 0; j < 8; ++j) acc[i][j] = {0.f, 0.f, 0.f, 0.f};

    const __hip_bfloat16* Ab = (const __hip_bfloat16*)A;
    const float* Af = (const float*)A;

    for (int k0 = 0; k0 < IN_CH; k0 += 64) {
        __syncthreads();
        // stage A (512 chunks of 16B) + B (2048 chunks), 10 per thread
        for (int ch = t; ch < 2560; ch += 256) {
            if (ch < 512) {
                int row = ch >> 3, off = (ch & 7) * 8;
                uint4 av = {0u, 0u, 0u, 0u};
                int gr = bm + row;
                if (gr < M) {
                    if (f32) {
                        const float* p = Af + (size_t)gr * IN_CH + k0 + off;
                        union { uint4 q; unsigned short us[8]; } u;
#pragma unroll
                        for (int i = 0; i < 8; ++i) u.us[i] = bf16_bits(p[i]);
                        av = u.q;
                    } else {
                        av = *(const uint4*)((const char*)Ab + ((size_t)gr * IN_CH + k0 + off) * 2);
                    }
                }
                *(uint4*)((char*)As + row * 144 + off * 2) = av;
            } else {
                int bc = ch - 512;
                int row = bc >> 3, off = (bc & 7) * 8;
                uint4 bv = *(const uint4*)((const char*)Bt + ((size_t)row * IN_CH + k0 + off) * 2);
                *(uint4*)((char*)Bs + row * 144 + off * 2) = bv;
            }
        }
        __syncthreads();
#pragma unroll
        for (int kk = 0; kk < 64; kk += 32) {
            short8 af[2], bf[8];
#pragma unroll
            for (int i = 0; i < 2; ++i)
                af[i] = *(const short8*)((const char*)As + (wm + i * 16 + l16) * 144 + (kk + quad * 8) * 2);
#pragma unroll
            for (int j = 0; j < 8; ++j)
                bf[j] = *(const short8*)((const char*)Bs + (wn + j * 16 + l16) * 144 + (kk + quad * 8) * 2);
#pragma unroll
            for (int i = 0; i < 2; ++i)
#pragma unroll
                for (int j = 0; j < 8; ++j)
                    acc[i][j] = __builtin_amdgcn_mfma_f32_16x16x32_bf16(af[i], bf[j], acc[i][j], 0, 0, 0);
        }
    }

#pragma unroll
    for (int i = 0; i < 2; ++i) {
#pragma unroll
        for (int j = 0; j < 8; ++j) {
            int nn = wn + j * 16 + l16;
            float bv = f32 ? ((const float*)bias)[nn]
                           : __bfloat162float(((const __hip_bfloat16*)bias)[nn]);
#pragma unroll
            for (int r = 0; r < 4; ++r) {
                int m = bm + wm + i * 16 + quad * 4 + r;
                if (m < M) {
                    float v = fmaxf(acc[i][j][r] + bv, 0.0f);
                    C[(size_t)m * HID_CH + nn] = __float2bfloat16(v);
                }
            }
        }
    }
}

// ---------- GEMM2: h0[M,64] = h1 @ w2 + b2; emit h0 (fp16) and g0=dinv*h0 ----------
// 64x64 tile, 4 waves 2x2 of 32x32, BK=64, K=256, single n-tile.
__global__ __launch_bounds__(256) void k_gemm2(
    const __hip_bfloat16* __restrict__ A, const __hip_bfloat16* __restrict__ Bt,
    const void* __restrict__ bias, const float* __restrict__ dinv,
    _Float16* __restrict__ h0h, _Float16* __restrict__ g0,
    int M, const int* __restrict__ meta)
{
    __shared__ __attribute__((aligned(16))) short As[64 * 72];
    __shared__ __attribute__((aligned(16))) short Bs[64 * 72];
    const int f32 = meta[1];
    const int t = threadIdx.x;
    const int bm = blockIdx.x * 64;
    const int wave = t >> 6, lane = t & 63;
    const int wm = (wave >> 1) * 32, wn = (wave & 1) * 32;
    const int quad = lane >> 4, l16 = lane & 15;

    floatx4 acc[2][2];
#pragma unroll
    for (int i = 0; i < 2; ++i)
#pragma unroll
        for (int j = 0; j < 2; ++j) acc[i][j] = {0.f, 0.f, 0.f, 0.f};

    for (int k0 = 0; k0 < HID_CH; k0 += 64) {
        __syncthreads();
        for (int ch = t; ch < 1024; ch += 256) {
            int row = (ch & 511) >> 3, off = (ch & 7) * 8;
            if (ch < 512) {
                uint4 av = {0u, 0u, 0u, 0u};
                int gr = bm + row;
                if (gr < M)
                    av = *(const uint4*)((const char*)A + ((size_t)gr * HID_CH + k0 + off) * 2);
                *(uint4*)((char*)As + row * 144 + off * 2) = av;
            } else {
                uint4 bv = *(const uint4*)((const char*)Bt + ((size_t)row * HID_CH + k0 + off) * 2);
                *(uint4*)((char*)Bs + row * 144 + off * 2) = bv;
            }
        }
        __syncthreads();
#pragma unroll
        for (int kk = 0; kk < 64; kk += 32) {
            short8 af[2], bf[2];
#pragma unroll
            for (int i = 0; i < 2; ++i)
                af[i] = *(const short8*)((const char*)As + (wm + i * 16 + l16) * 144 + (kk + quad * 8) * 2);
#pragma unroll
            for (int j = 0; j < 2; ++j)
                bf[j] = *(const short8*)((const char*)Bs + (wn + j * 16 + l16) * 144 + (kk + quad * 8) * 2);
#pragma unroll
            for (int i = 0; i < 2; ++i)
#pragma unroll
                for (int j = 0; j < 2; ++j)
                    acc[i][j] = __builtin_amdgcn_mfma_f32_16x16x32_bf16(af[i], bf[j], acc[i][j], 0, 0, 0);
        }
    }

#pragma unroll
    for (int i = 0; i < 2; ++i) {
#pragma unroll
        for (int j = 0; j < 2; ++j) {
            int nn = wn + j * 16 + l16;
            float bv = f32 ? ((const float*)bias)[nn]
                           : __bfloat162float(((const __hip_bfloat16*)bias)[nn]);
#pragma unroll
            for (int r = 0; r < 4; ++r) {
                int m = bm + wm + i * 16 + quad * 4 + r;
                if (m < M) {
                    float v = acc[i][j][r] + bv;
                    float dv = dinv[m];
                    h0h[(size_t)m * OUT_CH + nn] = (_Float16)v;
                    g0[(size_t)m * OUT_CH + nn] = (_Float16)(dv * v);
                }
            }
        }
    }
}

// ---------- propagation in g-space ----------
// S_i = g[i] + sum_{e in row i} g[col[e]]   (no per-edge value!)
// intermediate: g_out[i] = 0.9*dinv^2*S + 0.1*dinv*h0
// final:        out[i]   = 0.9*dinv*S   + 0.1*h0
// 8 lanes per node (16B fp16 each), 32 nodes per 256-thread block.
template<int FINAL>
__global__ __launch_bounds__(256) void k_prop(
    const _Float16* __restrict__ g, const _Float16* __restrict__ h0h,
    const int* __restrict__ rowptr, const int* __restrict__ col,
    const float* __restrict__ dinv,
    _Float16* __restrict__ gout, void* __restrict__ outfinal, int n,
    const int* __restrict__ meta)
{
    int gid = blockIdx.x * 32 + (threadIdx.x >> 3);
    if (gid >= n) return;
    int lane = threadIdx.x & 7;
    const half8* g8 = (const half8*)g;

    half8 sv = g8[(size_t)gid * 8 + lane];
    float acc[8];
#pragma unroll
    for (int i = 0; i < 8; ++i) acc[i] = (float)sv[i];

    int e0 = rowptr[gid], e1 = rowptr[gid + 1];
    int e = e0;
    for (; e + 4 <= e1; e += 4) {
        int c0 = col[e], c1 = col[e + 1], c2 = col[e + 2], c3 = col[e + 3];
        half8 v0 = g8[(size_t)c0 * 8 + lane];
        half8 v1 = g8[(size_t)c1 * 8 + lane];
        half8 v2 = g8[(size_t)c2 * 8 + lane];
        half8 v3 = g8[(size_t)c3 * 8 + lane];
#pragma unroll
        for (int i = 0; i < 8; ++i)
            acc[i] += ((float)v0[i] + (float)v1[i]) + ((float)v2[i] + (float)v3[i]);
    }
    for (; e < e1; ++e) {
        half8 v = g8[(size_t)col[e] * 8 + lane];
#pragma unroll
        for (int i = 0; i < 8; ++i) acc[i] += (float)v[i];
    }

    float dv = dinv[gid];
    half8 z = ((const half8*)h0h)[(size_t)gid * 8 + lane];

    if (FINAL) {
        float o[8];
#pragma unroll
        for (int i = 0; i < 8; ++i) o[i] = 0.9f * dv * acc[i] + 0.1f * (float)z[i];
        if (meta[1]) {
            float* of = (float*)outfinal + (size_t)gid * OUT_CH + lane * 8;
            float4 a = {o[0], o[1], o[2], o[3]}, b = {o[4], o[5], o[6], o[7]};
            *(float4*)of = a; *(float4*)(of + 4) = b;
        } else {
            struct alignas(16) BF8 { unsigned short v[8]; } ob;
#pragma unroll
            for (int i = 0; i < 8; ++i) ob.v[i] = bf16_bits(o[i]);
            *(BF8*)((unsigned short*)outfinal + (size_t)gid * OUT_CH + lane * 8) = ob;
        }
    } else {
        float w2v = 0.9f * dv * dv, w1v = 0.1f * dv;
        half8 o;
#pragma unroll
        for (int i = 0; i < 8; ++i) o[i] = (_Float16)(w2v * acc[i] + w1v * (float)z[i]);
        ((half8*)gout)[(size_t)gid * 8 + lane] = o;
    }
}

extern "C" void kernel_launch(void* const* d_in, const int* in_sizes, int n_in,
                              void* d_out, int out_size, void* d_ws, size_t ws_size,
                              hipStream_t stream) {
    const void* x    = d_in[0];
    const int* edges = (const int*)d_in[1];
    const void* w1   = d_in[2];
    const void* b1   = d_in[3];
    const void* w2   = d_in[4];
    const void* b2   = d_in[5];

    const int N = in_sizes[0] / IN_CH;   // 100000
    const int E = in_sizes[1] / 2;       // 1600000
    const int NB = (N + 1023) / 1024;

    size_t off = 0;
    auto carve = [&](size_t bytes) -> void* {
        void* r = (char*)d_ws + off;
        off += (bytes + 255) & ~(size_t)255;
        return r;
    };
    __hip_bfloat16* h1  = (__hip_bfloat16*)carve((size_t)N * HID_CH * 2);
    _Float16* h0h       = (_Float16*)carve((size_t)N * OUT_CH * 2);
    _Float16* gA        = (_Float16*)carve((size_t)N * OUT_CH * 2);
    _Float16* gB        = (_Float16*)carve((size_t)N * OUT_CH * 2);
    __hip_bfloat16* w1t = (__hip_bfloat16*)carve((size_t)IN_CH * HID_CH * 2);
    __hip_bfloat16* w2t = (__hip_bfloat16*)carve((size_t)HID_CH * OUT_CH * 2);
    int* cnt            = (int*)carve((size_t)N * 4);
    int* incl           = (int*)carve((size_t)NB * 1024 * 4);
    int* bsum           = (int*)carve(1024 * 4);
    int* boff           = (int*)carve(1024 * 4);
    int* rowptr         = (int*)carve((size_t)(N + 1) * 4);
    int* cursor         = (int*)carve((size_t)N * 4);
    float* dinv         = (float*)carve((size_t)N * 4);
    int* col            = (int*)carve((size_t)E * 4);
    int* meta           = (int*)carve(256);
    if (off > ws_size) return;

    hipMemsetAsync(cnt, 0, (size_t)N * 4, stream);
    hipMemsetAsync(meta, 0, 8, stream);

    k_probe<<<1, 256, 0, stream>>>(edges, (long long)2 * E,
                                   (const unsigned short*)x, meta);

    k_transpose<<<(IN_CH * HID_CH + 255) / 256, 256, 0, stream>>>(w1, w1t, IN_CH, HID_CH, meta);
    k_transpose<<<(HID_CH * OUT_CH + 255) / 256, 256, 0, stream>>>(w2, w2t, HID_CH, OUT_CH, meta);

    // CSR build first (dinv needed by k_gemm2 epilogue)
    const int EB = (E + 255) / 256;
    k_count<<<EB, 256, 0, stream>>>(edges, meta, E, cnt, N);
    k_scan1<<<NB, 1024, 0, stream>>>(cnt, incl, bsum, N);
    k_scan2<<<1, 64, 0, stream>>>(bsum, boff, NB);
    k_scan3<<<(N + 255) / 256, 256, 0, stream>>>(incl, cnt, boff, rowptr, cursor, N, E);
    k_dinv<<<(N + 255) / 256, 256, 0, stream>>>(cnt, dinv, N);
    k_fill<<<EB, 256, 0, stream>>>(edges, meta, E, cursor, col, N);

    // MLP
    const int MB = (N + 63) / 64;
    k_gemm1<<<MB, 256, 0, stream>>>(x, w1t, b1, h1, N, meta);
    k_gemm2<<<MB, 256, 0, stream>>>(h1, w2t, b2, dinv, h0h, gA, N, meta);

    // 10 propagation rounds in g-space; last writes d_out
    const int PB = (N + 31) / 32;
    const _Float16* cur = gA;
    _Float16* nxt = gB;
    for (int it = 0; it < 10; ++it) {
        if (it < 9) {
            k_prop<0><<<PB, 256, 0, stream>>>(cur, h0h, rowptr, col, dinv, nxt, nullptr, N, meta);
            const _Float16* tmp = cur; cur = nxt; nxt = (_Float16*)tmp;
        } else {
            k_prop<1><<<PB, 256, 0, stream>>>(cur, h0h, rowptr, col, dinv, nullptr, d_out, N, meta);
        }
    }
}